// Round 3
// baseline (3205.883 us; speedup 1.0000x reference)
//
#include <hip/hip_runtime.h>
#include <hip/hip_bf16.h>

#define N_SENT 2048
#define S_LEN  64
#define QL     16
#define NQ     128
#define NB     32
#define DD     256
#define VOCAB  100032

// ---------------- workspace layout (float offsets) ----------------
#define WS_X   0
#define WS_WX  (WS_X  + N_SENT*DD)
#define WS_Q   (WS_WX + N_SENT*DD)
#define WS_KS  (WS_Q  + NQ*DD)
#define WS_KVB (WS_KS + N_SENT*NB)
#define WS_HF  (WS_KVB+ NB*DD)
#define WS_Z   (WS_HF + NB*DD)

// ---------------- encoders: x[t] = sum_p emb[idx]*f_story[p] ----------------
__global__ __launch_bounds__(256) void encode_story(
    const int* __restrict__ inp, const float* __restrict__ emb,
    const float* __restrict__ f, float* __restrict__ X)
{
    const int t = blockIdx.x, d = threadIdx.x;
    __shared__ int idx[S_LEN];
    if (d < S_LEN) idx[d] = inp[t*S_LEN + d];
    __syncthreads();
    float acc = 0.f;
#pragma unroll 4
    for (int p = 0; p < S_LEN; ++p)
        acc += emb[(size_t)idx[p]*DD + d] * f[p*DD + d];
    X[t*DD + d] = acc;
}

__global__ __launch_bounds__(256) void encode_query(
    const int* __restrict__ qry, const float* __restrict__ emb,
    const float* __restrict__ f, float* __restrict__ Q)
{
    const int i = blockIdx.x, d = threadIdx.x;
    __shared__ int idx[QL];
    if (d < QL) idx[d] = qry[i*QL + d];
    __syncthreads();
    float acc = 0.f;
#pragma unroll
    for (int p = 0; p < QL; ++p)
        acc += emb[(size_t)idx[p]*DD + d] * f[p*DD + d];
    Q[i*DD + d] = acc;
}

// ---------------- WX[t] = W @ x[t];  KS[t][j] = keys_j . x[t] ----------------
__global__ __launch_bounds__(256) void wx_ks(
    const float* __restrict__ X, const float* __restrict__ W,
    const float* __restrict__ keys, float* __restrict__ WX, float* __restrict__ KS)
{
    const int t = blockIdx.x, n = threadIdx.x;
    __shared__ float xs[DD];
    xs[n] = X[t*DD + n];
    __syncthreads();
    float acc = 0.f;
    const float4* wr = (const float4*)&W[n*DD];
    const float4* xp = (const float4*)xs;
#pragma unroll 8
    for (int k4 = 0; k4 < 64; ++k4) {
        float4 w = wr[k4], x = xp[k4];
        acc += w.x*x.x + w.y*x.y + w.z*x.z + w.w*x.w;
    }
    WX[t*DD + n] = acc;
    if (n < NB) {
        float a2 = 0.f;
        const float4* kr = (const float4*)&keys[n*DD];
#pragma unroll 8
        for (int k4 = 0; k4 < 64; ++k4) {
            float4 kv = kr[k4], x = xp[k4];
            a2 += kv.x*x.x + kv.y*x.y + kv.z*x.z + kv.w*x.w;
        }
        KS[t*NB + n] = a2;
    }
}

// ---------------- KVB[j][n] = keys_j . V_row_n + bias[n] ----------------
__global__ __launch_bounds__(256) void kvb_kernel(
    const float* __restrict__ keys, const float* __restrict__ V,
    const float* __restrict__ bias, float* __restrict__ KVB)
{
    const int jj = blockIdx.x, n = threadIdx.x;
    __shared__ float ks[DD];
    ks[n] = keys[jj*DD + n];
    __syncthreads();
    float acc = bias[n];
    const float4* vr = (const float4*)&V[n*DD];
    const float4* kp = (const float4*)ks;
#pragma unroll 8
    for (int k4 = 0; k4 < 64; ++k4) {
        float4 v = vr[k4], k = kp[k4];
        acc += v.x*k.x + v.y*k.y + v.z*k.z + v.w*k.w;
    }
    KVB[jj*DD + n] = acc;
}

// ---------------- sequential scan: one chain per workgroup ----------------
// 512 threads, __launch_bounds__(512,2) -> 256-VGPR cap. U fragment (128
// floats/thread) is PINNED in VGPRs: each loaded component passes through an
// opaque asm so the compiler cannot re-load or rematerialize it in the loop.
// Thread owns output rows n0=tid&127, n1=n0+128 over k-range [r*64, r*64+64).
// Deferred normalization -> 2 barriers/step.
__global__ __launch_bounds__(512, 2) void scan_kernel(
    const float* __restrict__ X,  const float* __restrict__ WX,
    const float* __restrict__ KS, const float* __restrict__ KVB,
    const float* __restrict__ U,  const float* __restrict__ h0,
    const float* __restrict__ a_mem_p, float* __restrict__ Hf,
    float* __restrict__ HfOut)
{
    const int j   = blockIdx.x;
    const int tid = threadIdx.x;
    const int nb  = tid & 127;
    const int r   = tid >> 7;          // 0..3, k-range [r*64, r*64+64)
    const int n0  = nb, n1 = nb + 128;

    __shared__ float h_sh[DD];        // unnormalized h-hat
    __shared__ float part[4*DD];      // matvec k-range partials
    __shared__ float gred[4];         // gate-dot wave partials (on h-hat)
    __shared__ float nred[4];         // squared-norm wave partials (of h-hat)

    float4 u0[16], u1[16];
#pragma unroll
    for (int i = 0; i < 16; ++i) {
        u0[i] = *(const float4*)&U[n0*DD + r*64 + 4*i];
        u1[i] = *(const float4*)&U[n1*DD + r*64 + 4*i];
    }
    // Pin U in VGPRs: opaque provenance -> no remat/reload inside the loop.
#pragma unroll
    for (int i = 0; i < 16; ++i) {
        asm volatile("" : "+v"(u0[i].x), "+v"(u0[i].y), "+v"(u0[i].z), "+v"(u0[i].w));
        asm volatile("" : "+v"(u1[i].x), "+v"(u1[i].y), "+v"(u1[i].z), "+v"(u1[i].w));
    }
    const bool upd = (tid < DD);
    float hreg = 0.f, kvb = 0.f;
    if (upd) {
        hreg = h0[j*DD + tid];        // h0 used raw on first step (scale 1)
        kvb  = KVB[j*DD + tid];
        h_sh[tid] = hreg;
    }
    if (tid < 4) nred[tid] = 0.25f;   // sum = 1 -> inv = 1 on first step
    const float am = *a_mem_p;

    // prefetch t=0 operands
    float wxv = 0.f, xv = 0.f;
    if (upd) { wxv = WX[tid]; xv = X[tid]; }
    float ksv = KS[j];
    __syncthreads();

    for (int t = 0; t < N_SENT; ++t) {
        // inv from previous step's norm partials (visible via end barrier)
        const float inv = rsqrtf(nred[0] + nred[1] + nred[2] + nred[3]);

        // matvec partials on h-hat (scale applied after reduction)
        float acc0 = 0.f, acc1 = 0.f;
        const float4* hp = (const float4*)&h_sh[r*64];
#pragma unroll
        for (int i = 0; i < 16; ++i) {
            float4 hv = hp[i];
            acc0 += hv.x*u0[i].x + hv.y*u0[i].y + hv.z*u0[i].z + hv.w*u0[i].w;
            acc1 += hv.x*u1[i].x + hv.y*u1[i].y + hv.z*u1[i].z + hv.w*u1[i].w;
        }
        part[r*DD + n0] = acc0;
        part[r*DD + n1] = acc1;

        if (upd) {                    // gate-dot partial (h-hat . s)
            float gp = hreg * xv;
#pragma unroll
            for (int o = 32; o; o >>= 1) gp += __shfl_xor(gp, o);
            if ((tid & 63) == 0) gred[tid >> 6] = gp;
        }

        // prefetch t+1 operands (latency hides under this step's tail)
        const int tn = (t + 1 < N_SENT) ? t + 1 : t;
        float wxn = 0.f, xn = 0.f;
        if (upd) { wxn = WX[tn*DD + tid]; xn = X[tn*DD + tid]; }
        const float ksn = KS[tn*NB + j];

        __syncthreads();              // B1: part + gred ready
        if (upd) {
            float y = inv * (part[tid]        + part[DD + tid]
                           + part[2*DD + tid] + part[3*DD + tid]) + kvb + wxv;
            float hsv = (y >= 0.f) ? y : am * y;
            float gz  = inv * (gred[0] + gred[1] + gred[2] + gred[3]) + ksv;
            float g   = 1.f / (1.f + expf(-gz));
            float hn  = inv * hreg + g * hsv;     // normalized prev + update
            hreg = hn;
            h_sh[tid] = hn;                       // store unnormalized
            float sq = hn * hn;
#pragma unroll
            for (int o = 32; o; o >>= 1) sq += __shfl_xor(sq, o);
            if ((tid & 63) == 0) nred[tid >> 6] = sq;
        }
        wxv = wxn; xv = xn; ksv = ksn;
        __syncthreads();              // B2: h_sh + nred ready for next step
    }
    if (upd) {
        const float inv = rsqrtf(nred[0] + nred[1] + nred[2] + nred[3]);
        const float hf = hreg * inv;
        Hf[j*DD + tid]    = hf;
        HfOut[j*DD + tid] = hf;
    }
}

// ---------------- output module small part: c_ij, u_i, z_i ----------------
__global__ __launch_bounds__(256) void out_small(
    const float* __restrict__ Qe, const float* __restrict__ Hfm,
    const float* __restrict__ Hw, const float* __restrict__ Hb,
    const float* __restrict__ a_out_p, float* __restrict__ Z)
{
    const int i = blockIdx.x, d = threadIdx.x;
    __shared__ float hsh[NB*DD];
    __shared__ float red[4];
    __shared__ float csh[NB];
    __shared__ float ush[DD];
#pragma unroll
    for (int jj = 0; jj < NB; ++jj) hsh[jj*DD + d] = Hfm[jj*DD + d];
    const float qd = Qe[i*DD + d];
    __syncthreads();
    float s2 = 0.f;
#pragma unroll
    for (int jj = 0; jj < NB; ++jj) { float h = hsh[jj*DD + d]; s2 += h*h; }
    for (int jj = 0; jj < NB; ++jj) {
        float p = qd * hsh[jj*DD + d];
        float m = p;
#pragma unroll
        for (int o = 32; o; o >>= 1) m = fmaxf(m, __shfl_xor(m, o));
        if ((d & 63) == 0) red[d >> 6] = m;
        __syncthreads();
        m = fmaxf(fmaxf(red[0], red[1]), fmaxf(red[2], red[3]));
        __syncthreads();
        float e = expf(p - m);
#pragma unroll
        for (int o = 32; o; o >>= 1) e += __shfl_xor(e, o);
        if ((d & 63) == 0) red[d >> 6] = e;
        __syncthreads();
        if (d == 0) csh[jj] = m + logf(red[0] + red[1] + red[2] + red[3]);
        __syncthreads();
    }
    float u = qd * s2;
#pragma unroll
    for (int jj = 0; jj < NB; ++jj) u -= csh[jj] * hsh[jj*DD + d];
    ush[d] = u;
    __syncthreads();
    float acc = qd + Hb[d];
    const float4* hwr = (const float4*)&Hw[d*DD];
    const float4* up  = (const float4*)ush;
#pragma unroll 8
    for (int k4 = 0; k4 < 64; ++k4) {
        float4 w = hwr[k4], uu = up[k4];
        acc += w.x*uu.x + w.y*uu.y + w.z*uu.z + w.w*uu.w;
    }
    const float ao = *a_out_p;
    Z[i*DD + d] = (acc >= 0.f) ? acc : ao * acc;
}

// ---------------- big GEMM: Y[128,VOCAB] = Z @ Rw^T + Rb ----------------
__global__ __launch_bounds__(256) void out_gemm(
    const float* __restrict__ Z, const float* __restrict__ Rw,
    const float* __restrict__ Rb, float* __restrict__ Y)
{
    const int vt  = blockIdx.x * 64;
    const int tid = threadIdx.x;
    __shared__ float rw_sh[64*DD];   // 64 KB
    __shared__ float z_sh[64*DD];    // 64 KB
#pragma unroll
    for (int it = 0; it < 16; ++it) {
        int f = tid + it*256;
        int row = f >> 6, c = f & 63;
        float4 v = *(const float4*)&Rw[(size_t)(vt + row)*DD + 4*c];
        int u = c ^ ((row >> 2) & 7);
        *(float4*)&rw_sh[row*DD + 4*u] = v;
    }
    const int vg = tid & 15;
    const int ig = tid >> 4;
    const float4 rb4 = *(const float4*)&Rb[vt + vg*4];

    for (int ic = 0; ic < 2; ++ic) {
        const int i0 = ic * 64;
        __syncthreads();
#pragma unroll
        for (int it = 0; it < 16; ++it) {
            int f = tid + it*256;
            int row = f >> 6, c = f & 63;
            float4 v = *(const float4*)&Z[(i0 + row)*DD + 4*c];
            int u = c ^ ((row >> 2) & 7);
            *(float4*)&z_sh[row*DD + 4*u] = v;
        }
        __syncthreads();
        float acc[4][4];
#pragma unroll
        for (int b = 0; b < 4; ++b)
#pragma unroll
            for (int a = 0; a < 4; ++a) acc[b][a] = 0.f;
#pragma unroll 2
        for (int kc = 0; kc < 64; ++kc) {
            float4 ra[4], zb[4];
            const int ur = (kc ^ (vg & 7)) * 4;
            const int uz = (kc ^ (ig & 7)) * 4;
#pragma unroll
            for (int a = 0; a < 4; ++a) ra[a] = *(const float4*)&rw_sh[(vg*4 + a)*DD + ur];
#pragma unroll
            for (int b = 0; b < 4; ++b) zb[b] = *(const float4*)&z_sh[(ig*4 + b)*DD + uz];
#pragma unroll
            for (int b = 0; b < 4; ++b)
#pragma unroll
                for (int a = 0; a < 4; ++a)
                    acc[b][a] += zb[b].x*ra[a].x + zb[b].y*ra[a].y
                               + zb[b].z*ra[a].z + zb[b].w*ra[a].w;
        }
#pragma unroll
        for (int b = 0; b < 4; ++b) {
            int i = i0 + ig*4 + b;
            float4 o;
            o.x = acc[b][0] + rb4.x; o.y = acc[b][1] + rb4.y;
            o.z = acc[b][2] + rb4.z; o.w = acc[b][3] + rb4.w;
            *(float4*)&Y[(size_t)i*VOCAB + vt + vg*4] = o;
        }
    }
}

extern "C" void kernel_launch(void* const* d_in, const int* in_sizes, int n_in,
                              void* d_out, int out_size, void* d_ws, size_t ws_size,
                              hipStream_t stream)
{
    (void)in_sizes; (void)n_in; (void)out_size; (void)ws_size;
    const int*   inputs  = (const int*)  d_in[0];
    const int*   query   = (const int*)  d_in[1];
    const float* h0      = (const float*)d_in[2];
    const float* emb     = (const float*)d_in[3];
    const float* f_story = (const float*)d_in[4];
    const float* f_query = (const float*)d_in[5];
    const float* U       = (const float*)d_in[6];
    const float* V       = (const float*)d_in[7];
    const float* W       = (const float*)d_in[8];
    const float* bias    = (const float*)d_in[9];
    const float* keys    = (const float*)d_in[10];
    const float* a_mem   = (const float*)d_in[11];
    const float* Hw      = (const float*)d_in[12];
    const float* Hb      = (const float*)d_in[13];
    const float* Rw      = (const float*)d_in[14];
    const float* Rb      = (const float*)d_in[15];
    const float* a_out   = (const float*)d_in[16];

    float* ws  = (float*)d_ws;
    float* X   = ws + WS_X;
    float* WX  = ws + WS_WX;
    float* Qe  = ws + WS_Q;
    float* KS  = ws + WS_KS;
    float* KVB = ws + WS_KVB;
    float* Hf  = ws + WS_HF;
    float* Z   = ws + WS_Z;

    float* Y     = (float*)d_out;
    float* HfOut = Y + (size_t)NQ * VOCAB;

    encode_story<<<N_SENT, 256, 0, stream>>>(inputs, emb, f_story, X);
    encode_query<<<NQ,    256, 0, stream>>>(query,  emb, f_query, Qe);
    wx_ks      <<<N_SENT, 256, 0, stream>>>(X, W, keys, WX, KS);
    kvb_kernel <<<NB,     256, 0, stream>>>(keys, V, bias, KVB);
    scan_kernel<<<NB,     512, 0, stream>>>(X, WX, KS, KVB, U, h0, a_mem, Hf, HfOut);
    out_small  <<<NQ,     256, 0, stream>>>(Qe, Hf, Hw, Hb, a_out, Z);
    out_gemm   <<<VOCAB/64, 256, 0, stream>>>(Z, Rw, Rb, Y);
}

// Round 4
// 2803.154 us; speedup vs baseline: 1.1437x; 1.1437x over previous
//
#include <hip/hip_runtime.h>
#include <hip/hip_bf16.h>

#define N_SENT 2048
#define S_LEN  64
#define QL     16
#define NQ     128
#define NB     32
#define DD     256
#define VOCAB  100032

// ---------------- workspace layout (float offsets) ----------------
#define WS_X   0
#define WS_WX  (WS_X  + N_SENT*DD)
#define WS_Q   (WS_WX + N_SENT*DD)
#define WS_KS  (WS_Q  + NQ*DD)
#define WS_KVB (WS_KS + N_SENT*NB)
#define WS_HF  (WS_KVB+ NB*DD)
#define WS_Z   (WS_HF + NB*DD)

// ---------------- encoders: x[t] = sum_p emb[idx]*f_story[p] ----------------
__global__ __launch_bounds__(256) void encode_story(
    const int* __restrict__ inp, const float* __restrict__ emb,
    const float* __restrict__ f, float* __restrict__ X)
{
    const int t = blockIdx.x, d = threadIdx.x;
    __shared__ int idx[S_LEN];
    if (d < S_LEN) idx[d] = inp[t*S_LEN + d];
    __syncthreads();
    float acc = 0.f;
#pragma unroll 4
    for (int p = 0; p < S_LEN; ++p)
        acc += emb[(size_t)idx[p]*DD + d] * f[p*DD + d];
    X[t*DD + d] = acc;
}

__global__ __launch_bounds__(256) void encode_query(
    const int* __restrict__ qry, const float* __restrict__ emb,
    const float* __restrict__ f, float* __restrict__ Q)
{
    const int i = blockIdx.x, d = threadIdx.x;
    __shared__ int idx[QL];
    if (d < QL) idx[d] = qry[i*QL + d];
    __syncthreads();
    float acc = 0.f;
#pragma unroll
    for (int p = 0; p < QL; ++p)
        acc += emb[(size_t)idx[p]*DD + d] * f[p*DD + d];
    Q[i*DD + d] = acc;
}

// ---------------- WX[t] = W @ x[t];  KS[t][j] = keys_j . x[t] ----------------
__global__ __launch_bounds__(256) void wx_ks(
    const float* __restrict__ X, const float* __restrict__ W,
    const float* __restrict__ keys, float* __restrict__ WX, float* __restrict__ KS)
{
    const int t = blockIdx.x, n = threadIdx.x;
    __shared__ float xs[DD];
    xs[n] = X[t*DD + n];
    __syncthreads();
    float acc = 0.f;
    const float4* wr = (const float4*)&W[n*DD];
    const float4* xp = (const float4*)xs;
#pragma unroll 8
    for (int k4 = 0; k4 < 64; ++k4) {
        float4 w = wr[k4], x = xp[k4];
        acc += w.x*x.x + w.y*x.y + w.z*x.z + w.w*x.w;
    }
    WX[t*DD + n] = acc;
    if (n < NB) {
        float a2 = 0.f;
        const float4* kr = (const float4*)&keys[n*DD];
#pragma unroll 8
        for (int k4 = 0; k4 < 64; ++k4) {
            float4 kv = kr[k4], x = xp[k4];
            a2 += kv.x*x.x + kv.y*x.y + kv.z*x.z + kv.w*x.w;
        }
        KS[t*NB + n] = a2;
    }
}

// ---------------- KVB[j][n] = keys_j . V_row_n + bias[n] ----------------
__global__ __launch_bounds__(256) void kvb_kernel(
    const float* __restrict__ keys, const float* __restrict__ V,
    const float* __restrict__ bias, float* __restrict__ KVB)
{
    const int jj = blockIdx.x, n = threadIdx.x;
    __shared__ float ks[DD];
    ks[n] = keys[jj*DD + n];
    __syncthreads();
    float acc = bias[n];
    const float4* vr = (const float4*)&V[n*DD];
    const float4* kp = (const float4*)ks;
#pragma unroll 8
    for (int k4 = 0; k4 < 64; ++k4) {
        float4 v = vr[k4], k = kp[k4];
        acc += v.x*k.x + v.y*k.y + v.z*k.z + v.w*k.w;
    }
    KVB[jj*DD + n] = acc;
}

// ---------------- sequential scan: one chain per workgroup ----------------
// 512 threads. U fragment (128 floats/thread) must stay in VGPRs. Forcing
// functions: (1) 82KB LDS pad -> only 1 workgroup/CU fits -> occupancy is
// structurally 2 waves/SIMD, so the scheduler gains nothing by economizing
// registers below the 256 cap; (2) amdgpu_waves_per_eu(2,2) pins the
// occupancy target; (3) opaque asm pins on each U component block
// remat/reload. Deferred normalization -> 2 barriers/step.
__global__ __launch_bounds__(512)
__attribute__((amdgpu_waves_per_eu(2, 2)))
void scan_kernel(
    const float* __restrict__ X,  const float* __restrict__ WX,
    const float* __restrict__ KS, const float* __restrict__ KVB,
    const float* __restrict__ U,  const float* __restrict__ h0,
    const float* __restrict__ a_mem_p, float* __restrict__ Hf,
    float* __restrict__ HfOut)
{
    const int j   = blockIdx.x;
    const int tid = threadIdx.x;
    const int nb  = tid & 127;
    const int r   = tid >> 7;          // 0..3, k-range [r*64, r*64+64)
    const int n0  = nb, n1 = nb + 128;

    __shared__ float h_sh[DD];        // unnormalized h-hat
    __shared__ float part[4*DD];      // matvec k-range partials
    __shared__ float gred[4];         // gate-dot wave partials (on h-hat)
    __shared__ float nred[4];         // squared-norm wave partials (of h-hat)
    __shared__ float pad[19456];      // 76 KB occupancy limiter -> 1 block/CU
    ((volatile float*)pad)[tid] = 0.f;   // volatile touch: keeps pad allocated

    float4 u0[16], u1[16];
#pragma unroll
    for (int i = 0; i < 16; ++i) {
        u0[i] = *(const float4*)&U[n0*DD + r*64 + 4*i];
        u1[i] = *(const float4*)&U[n1*DD + r*64 + 4*i];
    }
    // Pin U in VGPRs: opaque provenance -> no remat/reload inside the loop.
#pragma unroll
    for (int i = 0; i < 16; ++i) {
        asm volatile("" : "+v"(u0[i].x), "+v"(u0[i].y), "+v"(u0[i].z), "+v"(u0[i].w));
        asm volatile("" : "+v"(u1[i].x), "+v"(u1[i].y), "+v"(u1[i].z), "+v"(u1[i].w));
    }
    const bool upd = (tid < DD);
    float hreg = 0.f, kvb = 0.f;
    if (upd) {
        hreg = h0[j*DD + tid];        // h0 used raw on first step (scale 1)
        kvb  = KVB[j*DD + tid];
        h_sh[tid] = hreg;
    }
    if (tid < 4) nred[tid] = 0.25f;   // sum = 1 -> inv = 1 on first step
    const float am = *a_mem_p;

    // prefetch t=0 operands
    float wxv = 0.f, xv = 0.f;
    if (upd) { wxv = WX[tid]; xv = X[tid]; }
    float ksv = KS[j];
    __syncthreads();

    for (int t = 0; t < N_SENT; ++t) {
        // inv from previous step's norm partials (visible via end barrier)
        const float inv = rsqrtf(nred[0] + nred[1] + nred[2] + nred[3]);

        // matvec partials on h-hat (scale applied after reduction)
        float acc0 = 0.f, acc1 = 0.f;
        const float4* hp = (const float4*)&h_sh[r*64];
#pragma unroll
        for (int i = 0; i < 16; ++i) {
            float4 hv = hp[i];
            acc0 += hv.x*u0[i].x + hv.y*u0[i].y + hv.z*u0[i].z + hv.w*u0[i].w;
            acc1 += hv.x*u1[i].x + hv.y*u1[i].y + hv.z*u1[i].z + hv.w*u1[i].w;
        }
        part[r*DD + n0] = acc0;
        part[r*DD + n1] = acc1;

        if (upd) {                    // gate-dot partial (h-hat . s)
            float gp = hreg * xv;
#pragma unroll
            for (int o = 32; o; o >>= 1) gp += __shfl_xor(gp, o);
            if ((tid & 63) == 0) gred[tid >> 6] = gp;
        }

        // prefetch t+1 operands (latency hides under this step's tail)
        const int tn = (t + 1 < N_SENT) ? t + 1 : t;
        float wxn = 0.f, xn = 0.f;
        if (upd) { wxn = WX[tn*DD + tid]; xn = X[tn*DD + tid]; }
        const float ksn = KS[tn*NB + j];

        __syncthreads();              // B1: part + gred ready
        if (upd) {
            float y = inv * (part[tid]        + part[DD + tid]
                           + part[2*DD + tid] + part[3*DD + tid]) + kvb + wxv;
            float hsv = (y >= 0.f) ? y : am * y;
            float gz  = inv * (gred[0] + gred[1] + gred[2] + gred[3]) + ksv;
            float g   = 1.f / (1.f + expf(-gz));
            float hn  = inv * hreg + g * hsv;     // normalized prev + update
            hreg = hn;
            h_sh[tid] = hn;                       // store unnormalized
            float sq = hn * hn;
#pragma unroll
            for (int o = 32; o; o >>= 1) sq += __shfl_xor(sq, o);
            if ((tid & 63) == 0) nred[tid >> 6] = sq;
        }
        wxv = wxn; xv = xn; ksv = ksn;
        __syncthreads();              // B2: h_sh + nred ready for next step
    }
    if (upd) {
        const float inv = rsqrtf(nred[0] + nred[1] + nred[2] + nred[3]);
        const float hf = hreg * inv;
        Hf[j*DD + tid]    = hf;
        HfOut[j*DD + tid] = hf;
    }
}

// ---------------- output module small part: c_ij, u_i, z_i ----------------
__global__ __launch_bounds__(256) void out_small(
    const float* __restrict__ Qe, const float* __restrict__ Hfm,
    const float* __restrict__ Hw, const float* __restrict__ Hb,
    const float* __restrict__ a_out_p, float* __restrict__ Z)
{
    const int i = blockIdx.x, d = threadIdx.x;
    __shared__ float hsh[NB*DD];
    __shared__ float red[4];
    __shared__ float csh[NB];
    __shared__ float ush[DD];
#pragma unroll
    for (int jj = 0; jj < NB; ++jj) hsh[jj*DD + d] = Hfm[jj*DD + d];
    const float qd = Qe[i*DD + d];
    __syncthreads();
    float s2 = 0.f;
#pragma unroll
    for (int jj = 0; jj < NB; ++jj) { float h = hsh[jj*DD + d]; s2 += h*h; }
    for (int jj = 0; jj < NB; ++jj) {
        float p = qd * hsh[jj*DD + d];
        float m = p;
#pragma unroll
        for (int o = 32; o; o >>= 1) m = fmaxf(m, __shfl_xor(m, o));
        if ((d & 63) == 0) red[d >> 6] = m;
        __syncthreads();
        m = fmaxf(fmaxf(red[0], red[1]), fmaxf(red[2], red[3]));
        __syncthreads();
        float e = expf(p - m);
#pragma unroll
        for (int o = 32; o; o >>= 1) e += __shfl_xor(e, o);
        if ((d & 63) == 0) red[d >> 6] = e;
        __syncthreads();
        if (d == 0) csh[jj] = m + logf(red[0] + red[1] + red[2] + red[3]);
        __syncthreads();
    }
    float u = qd * s2;
#pragma unroll
    for (int jj = 0; jj < NB; ++jj) u -= csh[jj] * hsh[jj*DD + d];
    ush[d] = u;
    __syncthreads();
    float acc = qd + Hb[d];
    const float4* hwr = (const float4*)&Hw[d*DD];
    const float4* up  = (const float4*)ush;
#pragma unroll 8
    for (int k4 = 0; k4 < 64; ++k4) {
        float4 w = hwr[k4], uu = up[k4];
        acc += w.x*uu.x + w.y*uu.y + w.z*uu.z + w.w*uu.w;
    }
    const float ao = *a_out_p;
    Z[i*DD + d] = (acc >= 0.f) ? acc : ao * acc;
}

// ---------------- big GEMM: Y[128,VOCAB] = Z @ Rw^T + Rb ----------------
__global__ __launch_bounds__(256) void out_gemm(
    const float* __restrict__ Z, const float* __restrict__ Rw,
    const float* __restrict__ Rb, float* __restrict__ Y)
{
    const int vt  = blockIdx.x * 64;
    const int tid = threadIdx.x;
    __shared__ float rw_sh[64*DD];   // 64 KB
    __shared__ float z_sh[64*DD];    // 64 KB
#pragma unroll
    for (int it = 0; it < 16; ++it) {
        int f = tid + it*256;
        int row = f >> 6, c = f & 63;
        float4 v = *(const float4*)&Rw[(size_t)(vt + row)*DD + 4*c];
        int u = c ^ ((row >> 2) & 7);
        *(float4*)&rw_sh[row*DD + 4*u] = v;
    }
    const int vg = tid & 15;
    const int ig = tid >> 4;
    const float4 rb4 = *(const float4*)&Rb[vt + vg*4];

    for (int ic = 0; ic < 2; ++ic) {
        const int i0 = ic * 64;
        __syncthreads();
#pragma unroll
        for (int it = 0; it < 16; ++it) {
            int f = tid + it*256;
            int row = f >> 6, c = f & 63;
            float4 v = *(const float4*)&Z[(i0 + row)*DD + 4*c];
            int u = c ^ ((row >> 2) & 7);
            *(float4*)&z_sh[row*DD + 4*u] = v;
        }
        __syncthreads();
        float acc[4][4];
#pragma unroll
        for (int b = 0; b < 4; ++b)
#pragma unroll
            for (int a = 0; a < 4; ++a) acc[b][a] = 0.f;
#pragma unroll 2
        for (int kc = 0; kc < 64; ++kc) {
            float4 ra[4], zb[4];
            const int ur = (kc ^ (vg & 7)) * 4;
            const int uz = (kc ^ (ig & 7)) * 4;
#pragma unroll
            for (int a = 0; a < 4; ++a) ra[a] = *(const float4*)&rw_sh[(vg*4 + a)*DD + ur];
#pragma unroll
            for (int b = 0; b < 4; ++b) zb[b] = *(const float4*)&z_sh[(ig*4 + b)*DD + uz];
#pragma unroll
            for (int b = 0; b < 4; ++b)
#pragma unroll
                for (int a = 0; a < 4; ++a)
                    acc[b][a] += zb[b].x*ra[a].x + zb[b].y*ra[a].y
                               + zb[b].z*ra[a].z + zb[b].w*ra[a].w;
        }
#pragma unroll
        for (int b = 0; b < 4; ++b) {
            int i = i0 + ig*4 + b;
            float4 o;
            o.x = acc[b][0] + rb4.x; o.y = acc[b][1] + rb4.y;
            o.z = acc[b][2] + rb4.z; o.w = acc[b][3] + rb4.w;
            *(float4*)&Y[(size_t)i*VOCAB + vt + vg*4] = o;
        }
    }
}

extern "C" void kernel_launch(void* const* d_in, const int* in_sizes, int n_in,
                              void* d_out, int out_size, void* d_ws, size_t ws_size,
                              hipStream_t stream)
{
    (void)in_sizes; (void)n_in; (void)out_size; (void)ws_size;
    const int*   inputs  = (const int*)  d_in[0];
    const int*   query   = (const int*)  d_in[1];
    const float* h0      = (const float*)d_in[2];
    const float* emb     = (const float*)d_in[3];
    const float* f_story = (const float*)d_in[4];
    const float* f_query = (const float*)d_in[5];
    const float* U       = (const float*)d_in[6];
    const float* V       = (const float*)d_in[7];
    const float* W       = (const float*)d_in[8];
    const float* bias    = (const float*)d_in[9];
    const float* keys    = (const float*)d_in[10];
    const float* a_mem   = (const float*)d_in[11];
    const float* Hw      = (const float*)d_in[12];
    const float* Hb      = (const float*)d_in[13];
    const float* Rw      = (const float*)d_in[14];
    const float* Rb      = (const float*)d_in[15];
    const float* a_out   = (const float*)d_in[16];

    float* ws  = (float*)d_ws;
    float* X   = ws + WS_X;
    float* WX  = ws + WS_WX;
    float* Qe  = ws + WS_Q;
    float* KS  = ws + WS_KS;
    float* KVB = ws + WS_KVB;
    float* Hf  = ws + WS_HF;
    float* Z   = ws + WS_Z;

    float* Y     = (float*)d_out;
    float* HfOut = Y + (size_t)NQ * VOCAB;

    encode_story<<<N_SENT, 256, 0, stream>>>(inputs, emb, f_story, X);
    encode_query<<<NQ,    256, 0, stream>>>(query,  emb, f_query, Qe);
    wx_ks      <<<N_SENT, 256, 0, stream>>>(X, W, keys, WX, KS);
    kvb_kernel <<<NB,     256, 0, stream>>>(keys, V, bias, KVB);
    scan_kernel<<<NB,     512, 0, stream>>>(X, WX, KS, KVB, U, h0, a_mem, Hf, HfOut);
    out_small  <<<NQ,     256, 0, stream>>>(Qe, Hf, Hw, Hb, a_out, Z);
    out_gemm   <<<VOCAB/64, 256, 0, stream>>>(Z, Rw, Rb, Y);
}